// Round 2
// 1123.261 us; speedup vs baseline: 1.3977x; 1.3977x over previous
//
#include <hip/hip_runtime.h>

// bf16 MFMA fragment types (gfx950: __builtin_amdgcn_mfma_f32_16x16x32_bf16 takes V8bf16)
typedef __bf16 bf16x8 __attribute__((ext_vector_type(8)));
typedef float  f32x4  __attribute__((ext_vector_type(4)));

__device__ __forceinline__ f32x4 mfma16(bf16x8 a, bf16x8 b, f32x4 c) {
    return __builtin_amdgcn_mfma_f32_16x16x32_bf16(a, b, c, 0, 0, 0);
}

__device__ __forceinline__ unsigned bpack2(float a, float b) {
    union { __bf16 h[2]; unsigned u; } z;
    z.h[0] = (__bf16)a; z.h[1] = (__bf16)b;
    return z.u;
}

// ---------------------------------------------------------------------------
// Kernel 0: weight prep. wqkv_t[c][k] = qkv_w[k][c] * (c<512 ? 1/sqrt(32) : 1)
//           wp_t[c][k]   = proj_w[k][c]
//           bias_eff[c]  = qkv_b[c] * (c<512 ? 1/sqrt(32) : 1)
// ---------------------------------------------------------------------------
__global__ void kprep(const float* __restrict__ qkvw, const float* __restrict__ qkvb,
                      const float* __restrict__ projw,
                      __bf16* __restrict__ wqkv_t, __bf16* __restrict__ wp_t,
                      float* __restrict__ bias_eff)
{
    const float s = 0.17677669529663687f; // 32^-0.5
    int idx = blockIdx.x * 256 + threadIdx.x;
    if (idx < 786432) {                       // qkv_w^T : [1536][512]
        int c = idx >> 9, k = idx & 511;
        float v = qkvw[k * 1536 + c];
        if (c < 512) v *= s;                  // fold q-scale into q columns
        wqkv_t[idx] = (__bf16)v;
    } else if (idx < 1048576) {               // proj_w^T : [512][512]
        int j = idx - 786432;
        int c = j >> 9, k = j & 511;
        wp_t[j] = (__bf16)projw[k * 512 + c];
    } else if (idx < 1050112) {               // bias (scaled for q part)
        int c = idx - 1048576;
        float v = qkvb[c];
        if (c < 512) v *= s;
        bias_eff[c] = v;
    }
}

// ---------------------------------------------------------------------------
// FUSED kernel: one block per window, 512 threads = 8 waves, 160 KiB LDS.
// LDS: xs [0,64K) = x staged A-frag-swizzled bf16 (shared);
//      per-wave 12 KB: q[0,4K) k[4K,8K) vt[8K,12K); p aliases [0,8K).
// Each wave owns 2 heads (h = w*2 + i). Waves run fully independent between
// the staging barrier and the pre-proj barrier -> 2 desynced waves/SIMD.
// PV outputs are held packed-bf16 in registers (oA/oB, 32 VGPRs); once every
// wave is past its last xs read, O tiles are written into xs (proj-A-frag
// layout) and the block runs the output projection, writing final fp32.
// ---------------------------------------------------------------------------
__global__ __launch_bounds__(512, 2) void kfused8(
    const float*  __restrict__ xin,       // [2048][60][512] fp32
    const __bf16* __restrict__ wqkv,      // [1536][512] transposed, q-scaled
    const float*  __restrict__ bias_eff,  // [1536]
    const __bf16* __restrict__ wp,        // [512][512] transposed
    const float*  __restrict__ projb,     // [512]
    float*        __restrict__ out)       // [2048][60][512] fp32
{
    const int b    = blockIdx.x;
    const int tid  = threadIdx.x;
    const int lane = tid & 63;
    const int w    = tid >> 6;            // 0..7
    const int q4   = lane >> 4;
    const int l15  = lane & 15;

    extern __shared__ char smem[];
    char* xs = smem;                        // [0, 65536): x swizzled, later O
    char* wb = smem + 65536 + w * 12288;    // per-wave scratch

    const f32x4 fzero = {0.f, 0.f, 0.f, 0.f};

    // ---- stage x: fp32 -> bf16, zero-pad rows 60..63, A-frag swizzle ----
#pragma unroll
    for (int j = 0; j < 8; ++j) {
        int ci = j * 512 + tid;             // 0..4095
        int r  = ci >> 6;
        int k0 = (ci & 63) << 3;
        float4 f0 = make_float4(0.f, 0.f, 0.f, 0.f), f1 = f0;
        if (r < 60) {
            const float4* s4 = reinterpret_cast<const float4*>(
                xin + ((size_t)b * 60 + r) * 512 + k0);
            f0 = s4[0]; f1 = s4[1];
        }
        bf16x8 v;
        v[0]=(__bf16)f0.x; v[1]=(__bf16)f0.y; v[2]=(__bf16)f0.z; v[3]=(__bf16)f0.w;
        v[4]=(__bf16)f1.x; v[5]=(__bf16)f1.y; v[6]=(__bf16)f1.z; v[7]=(__bf16)f1.w;
        int addr = ((((k0 >> 5) << 2) + (r >> 4)) * 64
                    + ((k0 >> 3) & 3) * 16 + (r & 15)) * 16;
        *reinterpret_cast<bf16x8*>(xs + addr) = v;
    }
    __syncthreads();

    unsigned oA[16], oB[16];                // packed bf16 PV outputs, 2 heads

    for (int i = 0; i < 2; ++i) {
        const int h = (w << 1) + i;
        __threadfence_block();   // prior round's p/vt LDS reads before writes

        // ---- Q/K/V projections for head h: [64x512] @ [512x32] ----
        for (int s = 0; s < 3; ++s) {
            const __bf16* wcol = wqkv + ((size_t)(s * 512 + h * 32 + l15) * 512) + q4 * 8;
            f32x4 acc[4][2];
#pragma unroll
            for (int mt = 0; mt < 4; ++mt)
#pragma unroll
                for (int n = 0; n < 2; ++n) acc[mt][n] = fzero;

#pragma unroll
            for (int kk = 0; kk < 16; ++kk) {
                bf16x8 a[4];
#pragma unroll
                for (int mt = 0; mt < 4; ++mt)
                    a[mt] = *reinterpret_cast<const bf16x8*>(
                        xs + (((kk << 2) + mt) * 64 + lane) * 16);
                bf16x8 bw[2];
#pragma unroll
                for (int n = 0; n < 2; ++n)
                    bw[n] = *reinterpret_cast<const bf16x8*>(
                        wcol + (size_t)(n * 16) * 512 + kk * 32);
#pragma unroll
                for (int mt = 0; mt < 4; ++mt)
#pragma unroll
                    for (int n = 0; n < 2; ++n)
                        acc[mt][n] = mfma16(a[mt], bw[n], acc[mt][n]);
            }
            float bs0 = bias_eff[s * 512 + h * 32 + l15];
            float bs1 = bias_eff[s * 512 + h * 32 + 16 + l15];
            // epilogue: C-layout -> swizzled per-wave LDS bufs
#pragma unroll
            for (int mt = 0; mt < 4; ++mt)
#pragma unroll
                for (int n = 0; n < 2; ++n)
#pragma unroll
                    for (int reg = 0; reg < 4; ++reg) {
                        float val = acc[mt][n][reg] + (n ? bs1 : bs0);
                        if (s < 2) {
                            // q/k: A/B-frag layout over [row][hd]
                            int hd = n * 16 + l15;
                            int addr = s * 4096
                                + ((mt * 64 + (hd >> 3) * 16 + q4 * 4 + reg) * 16)
                                + (hd & 7) * 2;
                            *reinterpret_cast<__bf16*>(wb + addr) = (__bf16)val;
                        } else {
                            // v: B-frag layout for PV (vt[hd][key])
                            int key = mt * 16 + q4 * 4 + reg;
                            int g   = ((mt >> 1) << 1) + n;   // (key>>5)*2 + (hd>>4)
                            int addr = 8192
                                + ((g * 64 + ((key >> 3) & 3) * 16 + l15) * 16)
                                + (key & 7) * 2;
                            *reinterpret_cast<__bf16*>(wb + addr) = (__bf16)val;
                        }
                    }
        }
        __threadfence_block();

        // ---- scores = Q K^T  (M=64,N=64,K=32 -> one MFMA K-step) ----
        bf16x8 qa[4], kb[4];
#pragma unroll
        for (int mt = 0; mt < 4; ++mt)
            qa[mt] = *reinterpret_cast<const bf16x8*>(wb + (mt * 64 + lane) * 16);
#pragma unroll
        for (int nt = 0; nt < 4; ++nt)
            kb[nt] = *reinterpret_cast<const bf16x8*>(wb + 4096 + (nt * 64 + lane) * 16);
        f32x4 sc[4][4];
#pragma unroll
        for (int mt = 0; mt < 4; ++mt)
#pragma unroll
            for (int nt = 0; nt < 4; ++nt)
                sc[mt][nt] = mfma16(qa[mt], kb[nt], fzero);

        // ---- masked softmax (keys 60..63 masked via l15>=12 in nt=3) ----
        float inv_rs[4][4];
#pragma unroll
        for (int mt = 0; mt < 4; ++mt)
#pragma unroll
            for (int reg = 0; reg < 4; ++reg) {
                float m0 = fmaxf(fmaxf(sc[mt][0][reg], sc[mt][1][reg]), sc[mt][2][reg]);
                float v3 = (l15 < 12) ? sc[mt][3][reg] : -3.0e38f;
                m0 = fmaxf(m0, v3);
#pragma unroll
                for (int d = 1; d < 16; d <<= 1)
                    m0 = fmaxf(m0, __shfl_xor(m0, d));
                float ssum = 0.f;
#pragma unroll
                for (int nt = 0; nt < 4; ++nt) {
                    float p = (nt == 3 && l15 >= 12) ? 0.f
                              : __expf(sc[mt][nt][reg] - m0);
                    sc[mt][nt][reg] = p;
                    ssum += p;
                }
#pragma unroll
                for (int d = 1; d < 16; d <<= 1)
                    ssum += __shfl_xor(ssum, d);
                inv_rs[mt][reg] = 1.f / ssum;   // normalize after PV
            }

        // ---- P (C-layout) -> LDS in A-frag layout (aliases q/k bufs) ----
#pragma unroll
        for (int mt = 0; mt < 4; ++mt)
#pragma unroll
            for (int nt = 0; nt < 4; ++nt)
#pragma unroll
                for (int reg = 0; reg < 4; ++reg) {
                    int addr = (((((nt >> 1) << 2) + mt) * 64)
                                + ((((nt & 1) << 1) + (l15 >> 3)) * 16 + q4 * 4 + reg)) * 16
                               + (l15 & 7) * 2;
                    *reinterpret_cast<__bf16*>(wb + addr) = (__bf16)sc[mt][nt][reg];
                }
        __threadfence_block();

        // ---- O = P V  (M=64,N=32,K=64 -> 2 K-steps) ----
        bf16x8 pa[4][2], vb[2][2];
#pragma unroll
        for (int mt = 0; mt < 4; ++mt)
#pragma unroll
            for (int ks = 0; ks < 2; ++ks)
                pa[mt][ks] = *reinterpret_cast<const bf16x8*>(
                    wb + (((ks << 2) + mt) * 64 + lane) * 16);
#pragma unroll
        for (int ks = 0; ks < 2; ++ks)
#pragma unroll
            for (int n = 0; n < 2; ++n)
                vb[ks][n] = *reinterpret_cast<const bf16x8*>(
                    wb + 8192 + (((ks << 1) + n) * 64 + lane) * 16);
        f32x4 o[4][2];
#pragma unroll
        for (int mt = 0; mt < 4; ++mt)
#pragma unroll
            for (int n = 0; n < 2; ++n) {
                o[mt][n] = mfma16(pa[mt][0], vb[0][n], fzero);
                o[mt][n] = mfma16(pa[mt][1], vb[1][n], o[mt][n]);
            }

        // ---- pack O*inv_rs into registers (bf16 pairs); xs still live ----
#pragma unroll
        for (int mt = 0; mt < 4; ++mt)
#pragma unroll
            for (int n = 0; n < 2; ++n)
#pragma unroll
                for (int rp = 0; rp < 2; ++rp) {
                    unsigned pk = bpack2(o[mt][n][2 * rp]     * inv_rs[mt][2 * rp],
                                         o[mt][n][2 * rp + 1] * inv_rs[mt][2 * rp + 1]);
                    if (i == 0) oA[mt * 4 + n * 2 + rp] = pk;
                    else        oB[mt * 4 + n * 2 + rp] = pk;
                }
    }

    // ---- all waves past their last xs read: write O into xs (proj-A-frag) ----
    __syncthreads();
    {
        const int h0 = w << 1;
#pragma unroll
        for (int mt = 0; mt < 4; ++mt)
#pragma unroll
            for (int n = 0; n < 2; ++n)
#pragma unroll
                for (int rp = 0; rp < 2; ++rp) {
                    int s0 = ((((h0 << 2) + mt) * 64)
                              + ((n * 2 + (l15 >> 3)) * 16 + q4 * 4 + rp * 2)) * 16
                             + (l15 & 7) * 2;
                    unsigned pa = oA[mt * 4 + n * 2 + rp];
                    unsigned pb = oB[mt * 4 + n * 2 + rp];
                    *reinterpret_cast<unsigned short*>(xs + s0)           = (unsigned short)pa;
                    *reinterpret_cast<unsigned short*>(xs + s0 + 16)      = (unsigned short)(pa >> 16);
                    // head h0+1 region is +4*64*16 = 4096 bytes
                    *reinterpret_cast<unsigned short*>(xs + s0 + 4096)    = (unsigned short)pb;
                    *reinterpret_cast<unsigned short*>(xs + s0 + 4096+16) = (unsigned short)(pb >> 16);
                }
    }
    __syncthreads();

    // ---- output projection: [64x512] @ [512x512], 8 waves x 2 passes ----
    float* outp = out + (size_t)b * 30720;
    for (int pass = 0; pass < 2; ++pass) {
        const int nt0 = (w << 2) + (pass << 1);   // 32 n-tiles over 8 waves x 2 passes x 2
        f32x4 acc[4][2];
#pragma unroll
        for (int mt = 0; mt < 4; ++mt)
#pragma unroll
            for (int n = 0; n < 2; ++n) acc[mt][n] = fzero;

#pragma unroll
        for (int kk = 0; kk < 16; ++kk) {
            bf16x8 a[4];
#pragma unroll
            for (int mt = 0; mt < 4; ++mt)
                a[mt] = *reinterpret_cast<const bf16x8*>(
                    xs + (((kk << 2) + mt) * 64 + lane) * 16);
            bf16x8 bw[2];
#pragma unroll
            for (int n = 0; n < 2; ++n)
                bw[n] = *reinterpret_cast<const bf16x8*>(
                    wp + (size_t)((nt0 + n) * 16 + l15) * 512 + kk * 32 + q4 * 8);
#pragma unroll
            for (int mt = 0; mt < 4; ++mt)
#pragma unroll
                for (int n = 0; n < 2; ++n)
                    acc[mt][n] = mfma16(a[mt], bw[n], acc[mt][n]);
        }
#pragma unroll
        for (int n = 0; n < 2; ++n) {
            int c = (nt0 + n) * 16 + l15;
            float bias = projb[c];
#pragma unroll
            for (int mt = 0; mt < 4; ++mt)
#pragma unroll
                for (int reg = 0; reg < 4; ++reg) {
                    int row = mt * 16 + q4 * 4 + reg;
                    if (row < 60)
                        outp[row * 512 + c] = acc[mt][n][reg] + bias;
                }
        }
    }
}

// ---------------------------------------------------------------------------
// FALLBACK path (harness-verified round-0 pipeline, 1570 us) — used only if
// the 160 KiB dynamic-LDS opt-in is rejected by the runtime.
// ---------------------------------------------------------------------------
__global__ __launch_bounds__(256, 1) void ka_fused(
    const float*  __restrict__ xin,
    const __bf16* __restrict__ wqkv,
    const float*  __restrict__ bias_eff,
    char*         __restrict__ aobase)
{
    const int b    = blockIdx.x;
    const int tid  = threadIdx.x;
    const int lane = tid & 63;
    const int w    = tid >> 6;
    const int q4   = lane >> 4;
    const int l15  = lane & 15;

    extern __shared__ char smem[];
    char* xs = smem;
    char* wb = smem + 65536 + w * 12288;

    const f32x4 fzero = {0.f, 0.f, 0.f, 0.f};

#pragma unroll
    for (int j = 0; j < 16; ++j) {
        int ci = j * 256 + tid;
        int r  = ci >> 6;
        int k0 = (ci & 63) << 3;
        float4 f0 = make_float4(0.f, 0.f, 0.f, 0.f), f1 = f0;
        if (r < 60) {
            const float4* s4 = reinterpret_cast<const float4*>(
                xin + ((size_t)b * 60 + r) * 512 + k0);
            f0 = s4[0]; f1 = s4[1];
        }
        bf16x8 v;
        v[0]=(__bf16)f0.x; v[1]=(__bf16)f0.y; v[2]=(__bf16)f0.z; v[3]=(__bf16)f0.w;
        v[4]=(__bf16)f1.x; v[5]=(__bf16)f1.y; v[6]=(__bf16)f1.z; v[7]=(__bf16)f1.w;
        int addr = ((((k0 >> 5) << 2) + (r >> 4)) * 64
                    + ((k0 >> 3) & 3) * 16 + (r & 15)) * 16;
        *reinterpret_cast<bf16x8*>(xs + addr) = v;
    }
    __syncthreads();

    for (int i = 0; i < 4; ++i) {
        const int h = (w << 2) + i;
        __threadfence_block();

        for (int s = 0; s < 3; ++s) {
            const __bf16* wcol = wqkv + ((size_t)(s * 512 + h * 32 + l15) * 512) + q4 * 8;
            f32x4 acc[4][2];
#pragma unroll
            for (int mt = 0; mt < 4; ++mt)
#pragma unroll
                for (int n = 0; n < 2; ++n) acc[mt][n] = fzero;

#pragma unroll
            for (int kk = 0; kk < 16; ++kk) {
                bf16x8 a[4];
#pragma unroll
                for (int mt = 0; mt < 4; ++mt)
                    a[mt] = *reinterpret_cast<const bf16x8*>(
                        xs + (((kk << 2) + mt) * 64 + lane) * 16);
                bf16x8 bw[2];
#pragma unroll
                for (int n = 0; n < 2; ++n)
                    bw[n] = *reinterpret_cast<const bf16x8*>(
                        wcol + (size_t)(n * 16) * 512 + kk * 32);
#pragma unroll
                for (int mt = 0; mt < 4; ++mt)
#pragma unroll
                    for (int n = 0; n < 2; ++n)
                        acc[mt][n] = mfma16(a[mt], bw[n], acc[mt][n]);
            }
            float bs0 = bias_eff[s * 512 + h * 32 + l15];
            float bs1 = bias_eff[s * 512 + h * 32 + 16 + l15];
#pragma unroll
            for (int mt = 0; mt < 4; ++mt)
#pragma unroll
                for (int n = 0; n < 2; ++n)
#pragma unroll
                    for (int reg = 0; reg < 4; ++reg) {
                        float val = acc[mt][n][reg] + (n ? bs1 : bs0);
                        if (s < 2) {
                            int hd = n * 16 + l15;
                            int addr = s * 4096
                                + ((mt * 64 + (hd >> 3) * 16 + q4 * 4 + reg) * 16)
                                + (hd & 7) * 2;
                            *reinterpret_cast<__bf16*>(wb + addr) = (__bf16)val;
                        } else {
                            int key = mt * 16 + q4 * 4 + reg;
                            int g   = ((mt >> 1) << 1) + n;
                            int addr = 8192
                                + ((g * 64 + ((key >> 3) & 3) * 16 + l15) * 16)
                                + (key & 7) * 2;
                            *reinterpret_cast<__bf16*>(wb + addr) = (__bf16)val;
                        }
                    }
        }
        __threadfence_block();

        bf16x8 qa[4], kb[4];
#pragma unroll
        for (int mt = 0; mt < 4; ++mt)
            qa[mt] = *reinterpret_cast<const bf16x8*>(wb + (mt * 64 + lane) * 16);
#pragma unroll
        for (int nt = 0; nt < 4; ++nt)
            kb[nt] = *reinterpret_cast<const bf16x8*>(wb + 4096 + (nt * 64 + lane) * 16);
        f32x4 sc[4][4];
#pragma unroll
        for (int mt = 0; mt < 4; ++mt)
#pragma unroll
            for (int nt = 0; nt < 4; ++nt)
                sc[mt][nt] = mfma16(qa[mt], kb[nt], fzero);

        float inv_rs[4][4];
#pragma unroll
        for (int mt = 0; mt < 4; ++mt)
#pragma unroll
            for (int reg = 0; reg < 4; ++reg) {
                float m0 = fmaxf(fmaxf(sc[mt][0][reg], sc[mt][1][reg]), sc[mt][2][reg]);
                float v3 = (l15 < 12) ? sc[mt][3][reg] : -3.0e38f;
                m0 = fmaxf(m0, v3);
#pragma unroll
                for (int d = 1; d < 16; d <<= 1)
                    m0 = fmaxf(m0, __shfl_xor(m0, d));
                float ssum = 0.f;
#pragma unroll
                for (int nt = 0; nt < 4; ++nt) {
                    float p = (nt == 3 && l15 >= 12) ? 0.f
                              : __expf(sc[mt][nt][reg] - m0);
                    sc[mt][nt][reg] = p;
                    ssum += p;
                }
#pragma unroll
                for (int d = 1; d < 16; d <<= 1)
                    ssum += __shfl_xor(ssum, d);
                inv_rs[mt][reg] = 1.f / ssum;
            }

#pragma unroll
        for (int mt = 0; mt < 4; ++mt)
#pragma unroll
            for (int nt = 0; nt < 4; ++nt)
#pragma unroll
                for (int reg = 0; reg < 4; ++reg) {
                    int addr = (((((nt >> 1) << 2) + mt) * 64)
                                + ((((nt & 1) << 1) + (l15 >> 3)) * 16 + q4 * 4 + reg)) * 16
                               + (l15 & 7) * 2;
                    *reinterpret_cast<__bf16*>(wb + addr) = (__bf16)sc[mt][nt][reg];
                }
        __threadfence_block();

        bf16x8 pa[4][2], vb[2][2];
#pragma unroll
        for (int mt = 0; mt < 4; ++mt)
#pragma unroll
            for (int ks = 0; ks < 2; ++ks)
                pa[mt][ks] = *reinterpret_cast<const bf16x8*>(
                    wb + (((ks << 2) + mt) * 64 + lane) * 16);
#pragma unroll
        for (int ks = 0; ks < 2; ++ks)
#pragma unroll
            for (int n = 0; n < 2; ++n)
                vb[ks][n] = *reinterpret_cast<const bf16x8*>(
                    wb + 8192 + (((ks << 1) + n) * 64 + lane) * 16);
        f32x4 o[4][2];
#pragma unroll
        for (int mt = 0; mt < 4; ++mt)
#pragma unroll
            for (int n = 0; n < 2; ++n) {
                o[mt][n] = mfma16(pa[mt][0], vb[0][n], fzero);
                o[mt][n] = mfma16(pa[mt][1], vb[1][n], o[mt][n]);
            }

        char* aob = aobase + (size_t)b * 122880;
#pragma unroll
        for (int mt = 0; mt < 4; ++mt)
#pragma unroll
            for (int n = 0; n < 2; ++n)
#pragma unroll
                for (int reg = 0; reg < 4; ++reg) {
                    float val = o[mt][n][reg] * inv_rs[mt][reg];
                    int addr = ((((h << 2) + mt) * 64)
                                + ((n * 2 + (l15 >> 3)) * 16 + q4 * 4 + reg)) * 16
                               + (l15 & 7) * 2;
                    *reinterpret_cast<__bf16*>(aob + addr) = (__bf16)val;
                }
    }
}

__global__ __launch_bounds__(256, 2) void kb_proj(
    const __bf16* __restrict__ wp,
    const float*  __restrict__ projb,
    char*         __restrict__ dout)
{
    const int b    = blockIdx.x;
    const int tid  = threadIdx.x;
    const int lane = tid & 63;
    const int w    = tid >> 6;
    const int q4   = lane >> 4;
    const int l15  = lane & 15;
    extern __shared__ char smem[];
    char* aob = dout + (size_t)b * 122880;
    const f32x4 fzero = {0.f, 0.f, 0.f, 0.f};

#pragma unroll
    for (int j = 0; j < 16; ++j) {
        int ci = j * 256 + tid;
        reinterpret_cast<uint4*>(smem)[ci] = reinterpret_cast<const uint4*>(aob)[ci];
    }
    __syncthreads();

    float* outp = reinterpret_cast<float*>(aob);
    for (int pass = 0; pass < 4; ++pass) {
        const int nt0 = pass * 8 + w * 2;
        f32x4 acc[4][2];
#pragma unroll
        for (int mt = 0; mt < 4; ++mt)
#pragma unroll
            for (int n = 0; n < 2; ++n) acc[mt][n] = fzero;

#pragma unroll
        for (int kk = 0; kk < 16; ++kk) {
            bf16x8 a[4];
#pragma unroll
            for (int mt = 0; mt < 4; ++mt)
                a[mt] = *reinterpret_cast<const bf16x8*>(
                    smem + (((kk << 2) + mt) * 64 + lane) * 16);
            bf16x8 bw[2];
#pragma unroll
            for (int n = 0; n < 2; ++n)
                bw[n] = *reinterpret_cast<const bf16x8*>(
                    wp + (size_t)((nt0 + n) * 16 + l15) * 512 + kk * 32 + q4 * 8);
#pragma unroll
            for (int mt = 0; mt < 4; ++mt)
#pragma unroll
                for (int n = 0; n < 2; ++n)
                    acc[mt][n] = mfma16(a[mt], bw[n], acc[mt][n]);
        }
#pragma unroll
        for (int n = 0; n < 2; ++n) {
            int c = (nt0 + n) * 16 + l15;
            float bias = projb[c];
#pragma unroll
            for (int mt = 0; mt < 4; ++mt)
#pragma unroll
                for (int reg = 0; reg < 4; ++reg) {
                    int row = mt * 16 + q4 * 4 + reg;
                    if (row < 60)
                        outp[row * 512 + c] = acc[mt][n][reg] + bias;
                }
        }
    }
}

// ---------------------------------------------------------------------------
extern "C" void kernel_launch(void* const* d_in, const int* in_sizes, int n_in,
                              void* d_out, int out_size, void* d_ws, size_t ws_size,
                              hipStream_t stream)
{
    const float* xin   = (const float*)d_in[0];  // [2048,60,512]
    const float* qkvw  = (const float*)d_in[1];  // [512,1536]
    const float* qkvb  = (const float*)d_in[2];  // [1536]
    const float* projw = (const float*)d_in[3];  // [512,512]
    const float* projb = (const float*)d_in[4];  // [512]

    __bf16* wqkv_t   = (__bf16*)d_ws;                          // 786432 elems
    __bf16* wp_t     = wqkv_t + 786432;                        // 262144 elems
    float*  bias_eff = (float*)((char*)d_ws + 2097152);        // 1536 fp32

    kprep<<<dim3(4102), dim3(256), 0, stream>>>(qkvw, qkvb, projw,
                                                wqkv_t, wp_t, bias_eff);

    hipError_t e = hipFuncSetAttribute(reinterpret_cast<const void*>(kfused8),
                                       hipFuncAttributeMaxDynamicSharedMemorySize, 163840);
    if (e == hipSuccess) {
        kfused8<<<dim3(2048), dim3(512), 163840, stream>>>(
            xin, wqkv_t, bias_eff, wp_t, projb, (float*)d_out);
    } else {
        (void)hipFuncSetAttribute(reinterpret_cast<const void*>(ka_fused),
                                  hipFuncAttributeMaxDynamicSharedMemorySize, 114688);
        (void)hipFuncSetAttribute(reinterpret_cast<const void*>(kb_proj),
                                  hipFuncAttributeMaxDynamicSharedMemorySize, 65536);
        ka_fused<<<dim3(2048), dim3(256), 114688, stream>>>(xin, wqkv_t, bias_eff,
                                                            (char*)d_out);
        kb_proj<<<dim3(2048), dim3(256), 65536, stream>>>(wp_t, projb, (char*)d_out);
    }
}

// Round 4
// 987.475 us; speedup vs baseline: 1.5899x; 1.1375x over previous
//
#include <hip/hip_runtime.h>

// bf16 MFMA fragment types (gfx950: __builtin_amdgcn_mfma_f32_16x16x32_bf16 takes V8bf16)
typedef __bf16 bf16x8 __attribute__((ext_vector_type(8)));
typedef float  f32x4  __attribute__((ext_vector_type(4)));

__device__ __forceinline__ f32x4 mfma16(bf16x8 a, bf16x8 b, f32x4 c) {
    return __builtin_amdgcn_mfma_f32_16x16x32_bf16(a, b, c, 0, 0, 0);
}

__device__ __forceinline__ unsigned bpack2(float a, float b) {
    union { __bf16 h[2]; unsigned u; } z;
    z.h[0] = (__bf16)a; z.h[1] = (__bf16)b;
    return z.u;
}

// ---------------------------------------------------------------------------
// Kernel 0 (v2): coalesced weight prep via LDS 64x64 tile transpose.
// blocks 0..191  : qkv_w [512][1536] -> wqkv_t [1536][512] (q cols scaled)
// blocks 192..255: proj_w [512][512] -> wp_t [512][512]
// block  256     : bias_eff
// ---------------------------------------------------------------------------
__global__ __launch_bounds__(256) void kprep2(
    const float* __restrict__ qkvw, const float* __restrict__ qkvb,
    const float* __restrict__ projw,
    __bf16* __restrict__ wqkv_t, __bf16* __restrict__ wp_t,
    float* __restrict__ bias_eff)
{
    __shared__ __bf16 tile[64][66];           // pad 66 -> conflict-free transpose
    const int bid = blockIdx.x;
    const int tid = threadIdx.x;
    const int sub = tid >> 6;                 // 0..3
    const int ln  = tid & 63;
    const float s = 0.17677669529663687f;     // 32^-0.5

    if (bid < 192) {
        int c0 = (bid % 24) * 64;             // c in [0,1536)
        int k0 = (bid / 24) * 64;             // k in [0,512)
#pragma unroll
        for (int r = 0; r < 16; ++r) {
            int kl = r * 4 + sub;
            int c  = c0 + ln;
            float v = qkvw[(size_t)(k0 + kl) * 1536 + c];   // coalesced read
            if (c < 512) v *= s;
            tile[kl][ln] = (__bf16)v;
        }
        __syncthreads();
#pragma unroll
        for (int r = 0; r < 16; ++r) {
            int cl = r * 4 + sub;
            wqkv_t[(size_t)(c0 + cl) * 512 + k0 + ln] = tile[ln][cl];  // coalesced write
        }
    } else if (bid < 256) {
        int t = bid - 192;
        int c0 = (t % 8) * 64, k0 = (t / 8) * 64;
#pragma unroll
        for (int r = 0; r < 16; ++r) {
            int kl = r * 4 + sub;
            tile[kl][ln] = (__bf16)projw[(size_t)(k0 + kl) * 512 + c0 + ln];
        }
        __syncthreads();
#pragma unroll
        for (int r = 0; r < 16; ++r) {
            int cl = r * 4 + sub;
            wp_t[(size_t)(c0 + cl) * 512 + k0 + ln] = tile[ln][cl];
        }
    } else {
        for (int j = tid; j < 1536; j += 256) {
            float v = qkvb[j];
            if (j < 512) v *= s;
            bias_eff[j] = v;
        }
    }
}

// ---------------------------------------------------------------------------
// FUSED kernel v2: one block per window, 512 threads = 8 waves, 160 KiB LDS.
// LDS: xs [0,64K) = x staged A-frag-swizzled bf16 (shared);
//      per-wave 12 KB: q[0,4K) k[4K,8K) vt[8K,12K); p aliases [0,8K).
// v2 changes vs round-2: QKV computes all 3 projections in ONE kk sweep
// (A-frag LDS reads cut 3x, 24 MFMA per a[4] load); proj phase merges its
// 2 passes (A-reads halved); x loads and out stores are nontemporal so the
// one-touch 500 MB stream doesn't evict the 2 MB weight set from L2.
// ---------------------------------------------------------------------------
__global__ __launch_bounds__(512, 2) void kfused8(
    const float*  __restrict__ xin,       // [2048][60][512] fp32
    const __bf16* __restrict__ wqkv,      // [1536][512] transposed, q-scaled
    const float*  __restrict__ bias_eff,  // [1536]
    const __bf16* __restrict__ wp,        // [512][512] transposed
    const float*  __restrict__ projb,     // [512]
    float*        __restrict__ out)       // [2048][60][512] fp32
{
    const int b    = blockIdx.x;
    const int tid  = threadIdx.x;
    const int lane = tid & 63;
    const int w    = tid >> 6;            // 0..7
    const int q4   = lane >> 4;
    const int l15  = lane & 15;

    extern __shared__ char smem[];
    char* xs = smem;                        // [0, 65536): x swizzled, later O
    char* wb = smem + 65536 + w * 12288;    // per-wave scratch

    const f32x4 fzero = {0.f, 0.f, 0.f, 0.f};

    // ---- stage x: fp32 -> bf16, zero-pad rows 60..63, A-frag swizzle ----
#pragma unroll
    for (int j = 0; j < 8; ++j) {
        int ci = j * 512 + tid;             // 0..4095
        int r  = ci >> 6;
        int k0 = (ci & 63) << 3;
        f32x4 f0 = fzero, f1 = fzero;
        if (r < 60) {
            const f32x4* s4 = reinterpret_cast<const f32x4*>(
                xin + ((size_t)b * 60 + r) * 512 + k0);
            f0 = __builtin_nontemporal_load(s4);
            f1 = __builtin_nontemporal_load(s4 + 1);
        }
        bf16x8 v;
        v[0]=(__bf16)f0[0]; v[1]=(__bf16)f0[1]; v[2]=(__bf16)f0[2]; v[3]=(__bf16)f0[3];
        v[4]=(__bf16)f1[0]; v[5]=(__bf16)f1[1]; v[6]=(__bf16)f1[2]; v[7]=(__bf16)f1[3];
        int addr = ((((k0 >> 5) << 2) + (r >> 4)) * 64
                    + ((k0 >> 3) & 3) * 16 + (r & 15)) * 16;
        *reinterpret_cast<bf16x8*>(xs + addr) = v;
    }
    __syncthreads();

    unsigned oA[16], oB[16];                // packed bf16 PV outputs, 2 heads

    for (int i = 0; i < 2; ++i) {
        const int h = (w << 1) + i;
        __threadfence_block();   // prior round's p/vt LDS reads before this round's writes

        // ---- Q/K/V projections for head h in ONE kk sweep ----
        const __bf16* wbase = wqkv + ((size_t)(h * 32 + l15) * 512) + q4 * 8;
        f32x4 acc3[3][4][2];
#pragma unroll
        for (int s = 0; s < 3; ++s)
#pragma unroll
            for (int mt = 0; mt < 4; ++mt)
#pragma unroll
                for (int n = 0; n < 2; ++n) acc3[s][mt][n] = fzero;

#pragma unroll
        for (int kk = 0; kk < 16; ++kk) {
            bf16x8 a[4];
#pragma unroll
            for (int mt = 0; mt < 4; ++mt)
                a[mt] = *reinterpret_cast<const bf16x8*>(
                    xs + (((kk << 2) + mt) * 64 + lane) * 16);
#pragma unroll
            for (int s = 0; s < 3; ++s) {
                bf16x8 bw0 = *reinterpret_cast<const bf16x8*>(
                    wbase + (size_t)s * 262144 + kk * 32);
                bf16x8 bw1 = *reinterpret_cast<const bf16x8*>(
                    wbase + (size_t)s * 262144 + 16 * 512 + kk * 32);
#pragma unroll
                for (int mt = 0; mt < 4; ++mt) {
                    acc3[s][mt][0] = mfma16(a[mt], bw0, acc3[s][mt][0]);
                    acc3[s][mt][1] = mfma16(a[mt], bw1, acc3[s][mt][1]);
                }
            }
        }
        // epilogue: C-layout -> swizzled per-wave LDS bufs
#pragma unroll
        for (int s = 0; s < 3; ++s) {
            float bs0 = bias_eff[s * 512 + h * 32 + l15];
            float bs1 = bias_eff[s * 512 + h * 32 + 16 + l15];
#pragma unroll
            for (int mt = 0; mt < 4; ++mt)
#pragma unroll
                for (int n = 0; n < 2; ++n)
#pragma unroll
                    for (int reg = 0; reg < 4; ++reg) {
                        float val = acc3[s][mt][n][reg] + (n ? bs1 : bs0);
                        if (s < 2) {
                            // q/k: A/B-frag layout over [row][hd]
                            int hd = n * 16 + l15;
                            int addr = s * 4096
                                + ((mt * 64 + (hd >> 3) * 16 + q4 * 4 + reg) * 16)
                                + (hd & 7) * 2;
                            *reinterpret_cast<__bf16*>(wb + addr) = (__bf16)val;
                        } else {
                            // v: B-frag layout for PV (vt[hd][key])
                            int key = mt * 16 + q4 * 4 + reg;
                            int g   = ((mt >> 1) << 1) + n;   // (key>>5)*2 + (hd>>4)
                            int addr = 8192
                                + ((g * 64 + ((key >> 3) & 3) * 16 + l15) * 16)
                                + (key & 7) * 2;
                            *reinterpret_cast<__bf16*>(wb + addr) = (__bf16)val;
                        }
                    }
        }
        __threadfence_block();

        // ---- scores = Q K^T  (M=64,N=64,K=32 -> one MFMA K-step) ----
        bf16x8 qa[4], kb[4];
#pragma unroll
        for (int mt = 0; mt < 4; ++mt)
            qa[mt] = *reinterpret_cast<const bf16x8*>(wb + (mt * 64 + lane) * 16);
#pragma unroll
        for (int nt = 0; nt < 4; ++nt)
            kb[nt] = *reinterpret_cast<const bf16x8*>(wb + 4096 + (nt * 64 + lane) * 16);
        f32x4 sc[4][4];
#pragma unroll
        for (int mt = 0; mt < 4; ++mt)
#pragma unroll
            for (int nt = 0; nt < 4; ++nt)
                sc[mt][nt] = mfma16(qa[mt], kb[nt], fzero);

        // ---- masked softmax (keys 60..63 masked via l15>=12 in nt=3) ----
        float inv_rs[4][4];
#pragma unroll
        for (int mt = 0; mt < 4; ++mt)
#pragma unroll
            for (int reg = 0; reg < 4; ++reg) {
                float m0 = fmaxf(fmaxf(sc[mt][0][reg], sc[mt][1][reg]), sc[mt][2][reg]);
                float v3 = (l15 < 12) ? sc[mt][3][reg] : -3.0e38f;
                m0 = fmaxf(m0, v3);
#pragma unroll
                for (int d = 1; d < 16; d <<= 1)
                    m0 = fmaxf(m0, __shfl_xor(m0, d));
                float ssum = 0.f;
#pragma unroll
                for (int nt = 0; nt < 4; ++nt) {
                    float p = (nt == 3 && l15 >= 12) ? 0.f
                              : __expf(sc[mt][nt][reg] - m0);
                    sc[mt][nt][reg] = p;
                    ssum += p;
                }
#pragma unroll
                for (int d = 1; d < 16; d <<= 1)
                    ssum += __shfl_xor(ssum, d);
                inv_rs[mt][reg] = 1.f / ssum;   // normalize after PV
            }

        // ---- P (C-layout) -> LDS in A-frag layout (aliases q/k bufs) ----
#pragma unroll
        for (int mt = 0; mt < 4; ++mt)
#pragma unroll
            for (int nt = 0; nt < 4; ++nt)
#pragma unroll
                for (int reg = 0; reg < 4; ++reg) {
                    int addr = (((((nt >> 1) << 2) + mt) * 64)
                                + ((((nt & 1) << 1) + (l15 >> 3)) * 16 + q4 * 4 + reg)) * 16
                               + (l15 & 7) * 2;
                    *reinterpret_cast<__bf16*>(wb + addr) = (__bf16)sc[mt][nt][reg];
                }
        __threadfence_block();

        // ---- O = P V  (M=64,N=32,K=64 -> 2 K-steps) ----
        bf16x8 pa[4][2], vb[2][2];
#pragma unroll
        for (int mt = 0; mt < 4; ++mt)
#pragma unroll
            for (int ks = 0; ks < 2; ++ks)
                pa[mt][ks] = *reinterpret_cast<const bf16x8*>(
                    wb + (((ks << 2) + mt) * 64 + lane) * 16);
#pragma unroll
        for (int ks = 0; ks < 2; ++ks)
#pragma unroll
            for (int n = 0; n < 2; ++n)
                vb[ks][n] = *reinterpret_cast<const bf16x8*>(
                    wb + 8192 + (((ks << 1) + n) * 64 + lane) * 16);
        f32x4 o[4][2];
#pragma unroll
        for (int mt = 0; mt < 4; ++mt)
#pragma unroll
            for (int n = 0; n < 2; ++n) {
                o[mt][n] = mfma16(pa[mt][0], vb[0][n], fzero);
                o[mt][n] = mfma16(pa[mt][1], vb[1][n], o[mt][n]);
            }

        // ---- pack O*inv_rs into registers (bf16 pairs); xs still live ----
#pragma unroll
        for (int mt = 0; mt < 4; ++mt)
#pragma unroll
            for (int n = 0; n < 2; ++n)
#pragma unroll
                for (int rp = 0; rp < 2; ++rp) {
                    unsigned pk = bpack2(o[mt][n][2 * rp]     * inv_rs[mt][2 * rp],
                                         o[mt][n][2 * rp + 1] * inv_rs[mt][2 * rp + 1]);
                    if (i == 0) oA[mt * 4 + n * 2 + rp] = pk;
                    else        oB[mt * 4 + n * 2 + rp] = pk;
                }
    }

    // ---- all waves past their last xs read: write O into xs (proj-A-frag) ----
    __syncthreads();
    {
        const int h0 = w << 1;
#pragma unroll
        for (int mt = 0; mt < 4; ++mt)
#pragma unroll
            for (int n = 0; n < 2; ++n)
#pragma unroll
                for (int rp = 0; rp < 2; ++rp) {
                    int s0 = ((((h0 << 2) + mt) * 64)
                              + ((n * 2 + (l15 >> 3)) * 16 + q4 * 4 + rp * 2)) * 16
                             + (l15 & 7) * 2;
                    unsigned pa = oA[mt * 4 + n * 2 + rp];
                    unsigned pb = oB[mt * 4 + n * 2 + rp];
                    *reinterpret_cast<unsigned short*>(xs + s0)           = (unsigned short)pa;
                    *reinterpret_cast<unsigned short*>(xs + s0 + 16)      = (unsigned short)(pa >> 16);
                    // head h0+1 region is +4*64*16 = 4096 bytes
                    *reinterpret_cast<unsigned short*>(xs + s0 + 4096)    = (unsigned short)pb;
                    *reinterpret_cast<unsigned short*>(xs + s0 + 4096+16) = (unsigned short)(pb >> 16);
                }
    }
    __syncthreads();

    // ---- output projection: [64x512] @ [512x512], 8 waves x 4 n-tiles,
    //      single kk sweep (A-reads shared across all 4 n-tiles) ----
    float* outp = out + (size_t)b * 30720;
    {
        f32x4 acc[4][4];                       // [mt][j], cols (w*4+j)*16
#pragma unroll
        for (int mt = 0; mt < 4; ++mt)
#pragma unroll
            for (int j = 0; j < 4; ++j) acc[mt][j] = fzero;

#pragma unroll
        for (int kk = 0; kk < 16; ++kk) {
            bf16x8 a[4];
#pragma unroll
            for (int mt = 0; mt < 4; ++mt)
                a[mt] = *reinterpret_cast<const bf16x8*>(
                    xs + (((kk << 2) + mt) * 64 + lane) * 16);
            bf16x8 bw[4];
#pragma unroll
            for (int j = 0; j < 4; ++j)
                bw[j] = *reinterpret_cast<const bf16x8*>(
                    wp + (size_t)(((w << 2) + j) * 16 + l15) * 512 + kk * 32 + q4 * 8);
#pragma unroll
            for (int mt = 0; mt < 4; ++mt)
#pragma unroll
                for (int j = 0; j < 4; ++j)
                    acc[mt][j] = mfma16(a[mt], bw[j], acc[mt][j]);
        }
#pragma unroll
        for (int j = 0; j < 4; ++j) {
            int c = ((w << 2) + j) * 16 + l15;
            float bias = projb[c];
#pragma unroll
            for (int mt = 0; mt < 4; ++mt)
#pragma unroll
                for (int reg = 0; reg < 4; ++reg) {
                    int row = mt * 16 + q4 * 4 + reg;
                    if (row < 60)
                        __builtin_nontemporal_store(acc[mt][j][reg] + bias,
                                                    &outp[row * 512 + c]);
                }
        }
    }
}

// ---------------------------------------------------------------------------
// FALLBACK path (round-0 pipeline, harness-verified) — used only if the
// 160 KiB dynamic-LDS opt-in is rejected by the runtime.
// ---------------------------------------------------------------------------
__global__ __launch_bounds__(256, 1) void ka_fused(
    const float*  __restrict__ xin,
    const __bf16* __restrict__ wqkv,
    const float*  __restrict__ bias_eff,
    char*         __restrict__ aobase)
{
    const int b    = blockIdx.x;
    const int tid  = threadIdx.x;
    const int lane = tid & 63;
    const int w    = tid >> 6;
    const int q4   = lane >> 4;
    const int l15  = lane & 15;

    extern __shared__ char smem[];
    char* xs = smem;
    char* wb = smem + 65536 + w * 12288;

    const f32x4 fzero = {0.f, 0.f, 0.f, 0.f};

#pragma unroll
    for (int j = 0; j < 16; ++j) {
        int ci = j * 256 + tid;
        int r  = ci >> 6;
        int k0 = (ci & 63) << 3;
        float4 f0 = make_float4(0.f, 0.f, 0.f, 0.f), f1 = f0;
        if (r < 60) {
            const float4* s4 = reinterpret_cast<const float4*>(
                xin + ((size_t)b * 60 + r) * 512 + k0);
            f0 = s4[0]; f1 = s4[1];
        }
        bf16x8 v;
        v[0]=(__bf16)f0.x; v[1]=(__bf16)f0.y; v[2]=(__bf16)f0.z; v[3]=(__bf16)f0.w;
        v[4]=(__bf16)f1.x; v[5]=(__bf16)f1.y; v[6]=(__bf16)f1.z; v[7]=(__bf16)f1.w;
        int addr = ((((k0 >> 5) << 2) + (r >> 4)) * 64
                    + ((k0 >> 3) & 3) * 16 + (r & 15)) * 16;
        *reinterpret_cast<bf16x8*>(xs + addr) = v;
    }
    __syncthreads();

    for (int i = 0; i < 4; ++i) {
        const int h = (w << 2) + i;
        __threadfence_block();

        for (int s = 0; s < 3; ++s) {
            const __bf16* wcol = wqkv + ((size_t)(s * 512 + h * 32 + l15) * 512) + q4 * 8;
            f32x4 acc[4][2];
#pragma unroll
            for (int mt = 0; mt < 4; ++mt)
#pragma unroll
                for (int n = 0; n < 2; ++n) acc[mt][n] = fzero;

#pragma unroll
            for (int kk = 0; kk < 16; ++kk) {
                bf16x8 a[4];
#pragma unroll
                for (int mt = 0; mt < 4; ++mt)
                    a[mt] = *reinterpret_cast<const bf16x8*>(
                        xs + (((kk << 2) + mt) * 64 + lane) * 16);
                bf16x8 bw[2];
#pragma unroll
                for (int n = 0; n < 2; ++n)
                    bw[n] = *reinterpret_cast<const bf16x8*>(
                        wcol + (size_t)(n * 16) * 512 + kk * 32);
#pragma unroll
                for (int mt = 0; mt < 4; ++mt)
#pragma unroll
                    for (int n = 0; n < 2; ++n)
                        acc[mt][n] = mfma16(a[mt], bw[n], acc[mt][n]);
            }
            float bs0 = bias_eff[s * 512 + h * 32 + l15];
            float bs1 = bias_eff[s * 512 + h * 32 + 16 + l15];
#pragma unroll
            for (int mt = 0; mt < 4; ++mt)
#pragma unroll
                for (int n = 0; n < 2; ++n)
#pragma unroll
                    for (int reg = 0; reg < 4; ++reg) {
                        float val = acc[mt][n][reg] + (n ? bs1 : bs0);
                        if (s < 2) {
                            int hd = n * 16 + l15;
                            int addr = s * 4096
                                + ((mt * 64 + (hd >> 3) * 16 + q4 * 4 + reg) * 16)
                                + (hd & 7) * 2;
                            *reinterpret_cast<__bf16*>(wb + addr) = (__bf16)val;
                        } else {
                            int key = mt * 16 + q4 * 4 + reg;
                            int g   = ((mt >> 1) << 1) + n;
                            int addr = 8192
                                + ((g * 64 + ((key >> 3) & 3) * 16 + l15) * 16)
                                + (key & 7) * 2;
                            *reinterpret_cast<__bf16*>(wb + addr) = (__bf16)val;
                        }
                    }
        }
        __threadfence_block();

        bf16x8 qa[4], kb[4];
#pragma unroll
        for (int mt = 0; mt < 4; ++mt)
            qa[mt] = *reinterpret_cast<const bf16x8*>(wb + (mt * 64 + lane) * 16);
#pragma unroll
        for (int nt = 0; nt < 4; ++nt)
            kb[nt] = *reinterpret_cast<const bf16x8*>(wb + 4096 + (nt * 64 + lane) * 16);
        f32x4 sc[4][4];
#pragma unroll
        for (int mt = 0; mt < 4; ++mt)
#pragma unroll
            for (int nt = 0; nt < 4; ++nt)
                sc[mt][nt] = mfma16(qa[mt], kb[nt], fzero);

        float inv_rs[4][4];
#pragma unroll
        for (int mt = 0; mt < 4; ++mt)
#pragma unroll
            for (int reg = 0; reg < 4; ++reg) {
                float m0 = fmaxf(fmaxf(sc[mt][0][reg], sc[mt][1][reg]), sc[mt][2][reg]);
                float v3 = (l15 < 12) ? sc[mt][3][reg] : -3.0e38f;
                m0 = fmaxf(m0, v3);
#pragma unroll
                for (int d = 1; d < 16; d <<= 1)
                    m0 = fmaxf(m0, __shfl_xor(m0, d));
                float ssum = 0.f;
#pragma unroll
                for (int nt = 0; nt < 4; ++nt) {
                    float p = (nt == 3 && l15 >= 12) ? 0.f
                              : __expf(sc[mt][nt][reg] - m0);
                    sc[mt][nt][reg] = p;
                    ssum += p;
                }
#pragma unroll
                for (int d = 1; d < 16; d <<= 1)
                    ssum += __shfl_xor(ssum, d);
                inv_rs[mt][reg] = 1.f / ssum;
            }

#pragma unroll
        for (int mt = 0; mt < 4; ++mt)
#pragma unroll
            for (int nt = 0; nt < 4; ++nt)
#pragma unroll
                for (int reg = 0; reg < 4; ++reg) {
                    int addr = (((((nt >> 1) << 2) + mt) * 64)
                                + ((((nt & 1) << 1) + (l15 >> 3)) * 16 + q4 * 4 + reg)) * 16
                               + (l15 & 7) * 2;
                    *reinterpret_cast<__bf16*>(wb + addr) = (__bf16)sc[mt][nt][reg];
                }
        __threadfence_block();

        bf16x8 pa[4][2], vb[2][2];
#pragma unroll
        for (int mt = 0; mt < 4; ++mt)
#pragma unroll
            for (int ks = 0; ks < 2; ++ks)
                pa[mt][ks] = *reinterpret_cast<const bf16x8*>(
                    wb + (((ks << 2) + mt) * 64 + lane) * 16);
#pragma unroll
        for (int ks = 0; ks < 2; ++ks)
#pragma unroll
            for (int n = 0; n < 2; ++n)
                vb[ks][n] = *reinterpret_cast<const bf16x8*>(
                    wb + 8192 + (((ks << 1) + n) * 64 + lane) * 16);
        f32x4 o[4][2];
#pragma unroll
        for (int mt = 0; mt < 4; ++mt)
#pragma unroll
            for (int n = 0; n < 2; ++n) {
                o[mt][n] = mfma16(pa[mt][0], vb[0][n], fzero);
                o[mt][n] = mfma16(pa[mt][1], vb[1][n], o[mt][n]);
            }

        char* aob = aobase + (size_t)b * 122880;
#pragma unroll
        for (int mt = 0; mt < 4; ++mt)
#pragma unroll
            for (int n = 0; n < 2; ++n)
#pragma unroll
                for (int reg = 0; reg < 4; ++reg) {
                    float val = o[mt][n][reg] * inv_rs[mt][reg];
                    int addr = ((((h << 2) + mt) * 64)
                                + ((n * 2 + (l15 >> 3)) * 16 + q4 * 4 + reg)) * 16
                               + (l15 & 7) * 2;
                    *reinterpret_cast<__bf16*>(aob + addr) = (__bf16)val;
                }
    }
}

__global__ __launch_bounds__(256, 2) void kb_proj(
    const __bf16* __restrict__ wp,
    const float*  __restrict__ projb,
    char*         __restrict__ dout)
{
    const int b    = blockIdx.x;
    const int tid  = threadIdx.x;
    const int lane = tid & 63;
    const int w    = tid >> 6;
    const int q4   = lane >> 4;
    const int l15  = lane & 15;
    extern __shared__ char smem[];
    char* aob = dout + (size_t)b * 122880;
    const f32x4 fzero = {0.f, 0.f, 0.f, 0.f};

#pragma unroll
    for (int j = 0; j < 16; ++j) {
        int ci = j * 256 + tid;
        reinterpret_cast<uint4*>(smem)[ci] = reinterpret_cast<const uint4*>(aob)[ci];
    }
    __syncthreads();

    float* outp = reinterpret_cast<float*>(aob);
    for (int pass = 0; pass < 4; ++pass) {
        const int nt0 = pass * 8 + w * 2;
        f32x4 acc[4][2];
#pragma unroll
        for (int mt = 0; mt < 4; ++mt)
#pragma unroll
            for (int n = 0; n < 2; ++n) acc[mt][n] = fzero;

#pragma unroll
        for (int kk = 0; kk < 16; ++kk) {
            bf16x8 a[4];
#pragma unroll
            for (int mt = 0; mt < 4; ++mt)
                a[mt] = *reinterpret_cast<const bf16x8*>(
                    smem + (((kk << 2) + mt) * 64 + lane) * 16);
            bf16x8 bw[2];
#pragma unroll
            for (int n = 0; n < 2; ++n)
                bw[n] = *reinterpret_cast<const bf16x8*>(
                    wp + (size_t)((nt0 + n) * 16 + l15) * 512 + kk * 32 + q4 * 8);
#pragma unroll
            for (int mt = 0; mt < 4; ++mt)
#pragma unroll
                for (int n = 0; n < 2; ++n)
                    acc[mt][n] = mfma16(a[mt], bw[n], acc[mt][n]);
        }
#pragma unroll
        for (int n = 0; n < 2; ++n) {
            int c = (nt0 + n) * 16 + l15;
            float bias = projb[c];
#pragma unroll
            for (int mt = 0; mt < 4; ++mt)
#pragma unroll
                for (int reg = 0; reg < 4; ++reg) {
                    int row = mt * 16 + q4 * 4 + reg;
                    if (row < 60)
                        outp[row * 512 + c] = acc[mt][n][reg] + bias;
                }
        }
    }
}

// ---------------------------------------------------------------------------
extern "C" void kernel_launch(void* const* d_in, const int* in_sizes, int n_in,
                              void* d_out, int out_size, void* d_ws, size_t ws_size,
                              hipStream_t stream)
{
    const float* xin   = (const float*)d_in[0];  // [2048,60,512]
    const float* qkvw  = (const float*)d_in[1];  // [512,1536]
    const float* qkvb  = (const float*)d_in[2];  // [1536]
    const float* projw = (const float*)d_in[3];  // [512,512]
    const float* projb = (const float*)d_in[4];  // [512]

    __bf16* wqkv_t   = (__bf16*)d_ws;                          // 786432 elems
    __bf16* wp_t     = wqkv_t + 786432;                        // 262144 elems
    float*  bias_eff = (float*)((char*)d_ws + 2097152);        // 1536 fp32

    kprep2<<<dim3(257), dim3(256), 0, stream>>>(qkvw, qkvb, projw,
                                                wqkv_t, wp_t, bias_eff);

    hipError_t e = hipFuncSetAttribute(reinterpret_cast<const void*>(kfused8),
                                       hipFuncAttributeMaxDynamicSharedMemorySize, 163840);
    if (e == hipSuccess) {
        kfused8<<<dim3(2048), dim3(512), 163840, stream>>>(
            xin, wqkv_t, bias_eff, wp_t, projb, (float*)d_out);
    } else {
        (void)hipFuncSetAttribute(reinterpret_cast<const void*>(ka_fused),
                                  hipFuncAttributeMaxDynamicSharedMemorySize, 114688);
        (void)hipFuncSetAttribute(reinterpret_cast<const void*>(kb_proj),
                                  hipFuncAttributeMaxDynamicSharedMemorySize, 65536);
        ka_fused<<<dim3(2048), dim3(256), 114688, stream>>>(xin, wqkv_t, bias_eff,
                                                            (char*)d_out);
        kb_proj<<<dim3(2048), dim3(256), 65536, stream>>>(wp_t, projb, (char*)d_out);
    }
}